// Round 7
// baseline (1178.729 us; speedup 1.0000x reference)
//
#include <hip/hip_runtime.h>

// VectorQuantizer: z (8,64,16,64,64) f32, emb (512,64) f32.
// N = 524288, D = 64, K = 512.
// out flat = [ z_q_st (33554432 f32) | loss (1 f32) | indices (524288 f32) ]
//
// Bit-exact replication of the checker's np fp32 arithmetic (verified R3):
//   d[n,k] = fl( fmaf(-2, M_nk, zz_n) + ee_k ),  M_nk = sequential fma chain
//   c=0..63; zz/ee = numpy pairwise sum-of-squares (n=64 pattern);
//   argmin = strict <, ascending k.
//
// R12: R11 (R=4) regressed: 4 z-rows (256 regs) cannot fit the 256-reg arch
// VGPR file VALU can address -> AGPR shuttle returned (VALUBusy 410us = 2x
// floor) and 1 wave/SIMD had no TLP to hide anything. R=2 is the max with
// z fully arch-resident; R10's 617us is DS-instruction-bound (16 uniform
// ds_read_b128/k x ~12cyc x 16 waves/CU = 655us model). This round splits
// the e-stream across PIPES and halves VALU issue:
//  (a) chunks c4 0..3 from LDS (filled ONCE, 32KB, no passes) -> DS 164us;
//      chunks 4..15 + ee via uniform-address global_load (VGPR-laundered
//      index so the compiler can't scalarize to SMEM, which is out-of-order)
//      -> one L1 transaction each, broadcast, separate pipe (~100-170us).
//      __syncthreads every 32 k phase-locks waves -> 6KB window L1-hits.
//  (b) v_pk_fma_f32: rows a,b packed {za[c],zb[c]} share the e scalar; per
//      component it's the SAME IEEE fma chain in the SAME order -> bit-exact,
//      but one instruction for two FMAs (issue floor 218 -> ~120us).

#define NK       512
#define DD       64
#define LOSS_OFF 33554432
#define IDX_OFF  33554433
#define EE_FOFF  4            // float offset of ee[512] in ws (byte 16)

typedef float f32x2 __attribute__((ext_vector_type(2)));
typedef float f32x4 __attribute__((ext_vector_type(4)));

// numpy pairwise_sum of squares, n=64 (scalar form, for vq_ee).
__device__ __forceinline__ float np_sumsq64(const float* v) {
#pragma clang fp contract(off)
    float r[8];
    #pragma unroll
    for (int j = 0; j < 8; ++j) {
        float s = v[j] * v[j];
        r[j] = s;
    }
    #pragma unroll
    for (int i = 8; i < 64; i += 8) {
        #pragma unroll
        for (int j = 0; j < 8; ++j) {
            float s = v[i + j] * v[i + j];
            r[j] += s;
        }
    }
    return ((r[0] + r[1]) + (r[2] + r[3])) + ((r[4] + r[5]) + (r[6] + r[7]));
}

__global__ void vq_ee(const float* __restrict__ emb, float* __restrict__ ws) {
    const int k = blockIdx.x * 256 + threadIdx.x;      // grid 2 x 256
    if (blockIdx.x == 0 && threadIdx.x == 0) {         // zero fp64 loss acc
        ((double*)ws)[0] = 0.0;
        ((double*)ws)[1] = 0.0;
    }
    float row[DD];
    const float* er = emb + k * DD;
    #pragma unroll
    for (int c = 0; c < DD; ++c) row[c] = er[c];
    ws[EE_FOFF + k] = np_sumsq64(row);
}

__global__ __launch_bounds__(256)
__attribute__((amdgpu_waves_per_eu(2, 2)))
void vq_main(const float* __restrict__ z, const float* __restrict__ emb,
             float* __restrict__ out, float* __restrict__ ws) {
#pragma clang fp contract(off)
    __shared__ f32x4 elds[NK * 4];     // 32 KB: chunks c4=0..3 of every row

    const int tid = threadIdx.x;
    const int n0  = blockIdx.x * 512 + tid;            // grid 1024 x 256
    const int n1  = n0 + 256;                          // same b (512 | 65536)
    const int b   = n0 >> 16;
    const int sp  = n0 & 65535;
    const float* zp0 = z + ((size_t)b << 22) + sp;
    const float* zp1 = zp0 + 256;

    const f32x4* eg = (const f32x4*)emb;

    // one-time LDS fill: chunks 0..3 of all 512 rows (idx = k*4 + c4)
    #pragma unroll
    for (int r = 0; r < 8; ++r) {
        const int idx = r * 256 + tid;
        elds[idx] = eg[(idx >> 2) * 16 + (idx & 3)];
    }

    // z rows packed: zpk[c] = {za[c], zb[c]} -> 128 arch VGPRs
    f32x2 zpk[DD];
    #pragma unroll
    for (int c = 0; c < DD; ++c) zpk[c].x = zp0[(size_t)c << 16];
    #pragma unroll
    for (int c = 0; c < DD; ++c) zpk[c].y = zp1[(size_t)c << 16];

    // packed numpy pairwise sumsq (per-component identical to np_sumsq64)
    f32x2 rr[8];
    #pragma unroll
    for (int j = 0; j < 8; ++j) {
        f32x2 s = zpk[j] * zpk[j];
        rr[j] = s;
    }
    #pragma unroll
    for (int i = 8; i < 64; i += 8) {
        #pragma unroll
        for (int j = 0; j < 8; ++j) {
            f32x2 s = zpk[i + j] * zpk[i + j];
            rr[j] += s;
        }
    }
    const f32x2 zzpk = ((rr[0] + rr[1]) + (rr[2] + rr[3]))
                     + ((rr[4] + rr[5]) + (rr[6] + rr[7]));

    const f32x2* eeg = (const f32x2*)(ws + EE_FOFF);

    float best0 = 3.4e38f, best1 = 3.4e38f;
    int   bi0   = 0,        bi1   = 0;

    #pragma unroll 1
    for (int ko = 0; ko < 256; ++ko) {                 // 2 k per iteration
        if ((ko & 15) == 0) __syncthreads();           // phase-lock (L1 window);
                                                       // ko=0 doubles as fill barrier
        int eei = ko;
        asm volatile("" : "+v"(eei));                  // keep VMEM (not SMEM)
        const f32x2 ee2 = eeg[eei];                    // uniform broadcast load
        #pragma unroll
        for (int ki = 0; ki < 2; ++ki) {
            const int k = ko * 2 + ki;
            int ebase = k * 16;
            asm volatile("" : "+v"(ebase));            // launder -> global_load
            f32x2 m = { 0.f, 0.f };                    // two chains, packed
            #pragma unroll
            for (int c4 = 0; c4 < 4; ++c4) {           // c 0..15 from LDS
                const f32x4 e = elds[(k << 2) + c4];
                const int c = c4 * 4;
                f32x2 es;
                es = (f32x2){ e.x, e.x }; m = __builtin_elementwise_fma(zpk[c + 0], es, m);
                es = (f32x2){ e.y, e.y }; m = __builtin_elementwise_fma(zpk[c + 1], es, m);
                es = (f32x2){ e.z, e.z }; m = __builtin_elementwise_fma(zpk[c + 2], es, m);
                es = (f32x2){ e.w, e.w }; m = __builtin_elementwise_fma(zpk[c + 3], es, m);
            }
            #pragma unroll
            for (int c4 = 4; c4 < 16; ++c4) {          // c 16..63 from L1/L2
                const f32x4 e = eg[ebase + c4];        // uniform broadcast load
                const int c = c4 * 4;
                f32x2 es;
                es = (f32x2){ e.x, e.x }; m = __builtin_elementwise_fma(zpk[c + 0], es, m);
                es = (f32x2){ e.y, e.y }; m = __builtin_elementwise_fma(zpk[c + 1], es, m);
                es = (f32x2){ e.z, e.z }; m = __builtin_elementwise_fma(zpk[c + 2], es, m);
                es = (f32x2){ e.w, e.w }; m = __builtin_elementwise_fma(zpk[c + 3], es, m);
            }
            const float ee = (ki == 0) ? ee2.x : ee2.y;
            f32x2 d2 = __builtin_elementwise_fma((f32x2){ -2.f, -2.f }, m, zzpk);
            d2 += (f32x2){ ee, ee };                   // separate rounding, as np
            if (d2.x < best0) { best0 = d2.x; bi0 = k; }   // strict <, asc k
            if (d2.y < best1) { best1 = d2.y; bi1 = k; }
        }
    }

    // epilogue x2: gather z_q rows (emb L2-hot, divergent bi), coalesced writes
    float* op0 = out + ((size_t)b << 22) + sp;
    float* op1 = op0 + 256;
    const float4* br0 = (const float4*)(emb + bi0 * DD);
    const float4* br1 = (const float4*)(emb + bi1 * DD);
    float lsum = 0.f;
    #pragma unroll
    for (int c4 = 0; c4 < 16; ++c4) {
        float4 e0 = br0[c4];
        float4 e1 = br1[c4];
        float eq0[4] = { e0.x, e0.y, e0.z, e0.w };
        float eq1[4] = { e1.x, e1.y, e1.z, e1.w };
        #pragma unroll
        for (int j = 0; j < 4; ++j) {
            const int c = c4 * 4 + j;
            float da = eq0[j] - zpk[c].x;
            float db = eq1[j] - zpk[c].y;
            lsum = fmaf(da, da, lsum);
            lsum = fmaf(db, db, lsum);
            op0[(size_t)c << 16] = eq0[j];
            op1[(size_t)c << 16] = eq1[j];
        }
    }
    out[IDX_OFF + n0] = (float)bi0;
    out[IDX_OFF + n1] = (float)bi1;

    #pragma unroll
    for (int off = 32; off > 0; off >>= 1) lsum += __shfl_down(lsum, off);
    if ((tid & 63) == 0)
        atomicAdd((double*)ws, (double)lsum);          // fp64 final accumulation
}

__global__ void vq_finalize(const float* __restrict__ ws, float* __restrict__ out) {
    out[LOSS_OFF] = (float)(((const double*)ws)[0] * (1.25 / 33554432.0));
}

extern "C" void kernel_launch(void* const* d_in, const int* in_sizes, int n_in,
                              void* d_out, int out_size, void* d_ws, size_t ws_size,
                              hipStream_t stream) {
    const float* z   = (const float*)d_in[0];
    const float* emb = (const float*)d_in[1];
    float* out = (float*)d_out;
    float* ws  = (float*)d_ws;

    vq_ee<<<dim3(2), dim3(256), 0, stream>>>(emb, ws);
    vq_main<<<dim3(1024), dim3(256), 0, stream>>>(z, emb, out, ws);
    vq_finalize<<<dim3(1), dim3(1), 0, stream>>>(ws, out);
}